// Round 8
// baseline (241.100 us; speedup 1.0000x reference)
//
#include <hip/hip_runtime.h>

#define BATCH 8
#define NPTS  12000
#define FDIM  128
#define SDIM  16
#define ODIM  128
#define KDIM  (SDIM * FDIM)      // 2048
#define MTOT  (BATCH * NPTS)     // 96000

#define BM 128
#define BK 64                    // W rows: 128 B = 8 x 16B chunks (verified swizzle)

#define NTILES 94                // ceil(12000 / 128)
#define XELEMS (BATCH * NPTS * FDIM)   // 12,288,000
#define WELEMS (ODIM * KDIM)           // 262,144
#define XBYTES ((size_t)XELEMS * 2)
#define WBYTES ((size_t)WELEMS * 2)

#define SCW 68                   // scratch stride (floats): 16B-aligned, bank-spread

typedef __bf16 bf16x4 __attribute__((ext_vector_type(4)));
typedef __bf16 bf16x8 __attribute__((ext_vector_type(8)));
typedef float  f32x4  __attribute__((ext_vector_type(4)));
typedef float  f32x8  __attribute__((ext_vector_type(8)));

#define AS1(p) ((const __attribute__((address_space(1))) void*)(p))
#define AS3(p) ((__attribute__((address_space(3))) void*)(p))

// ---------------- pre-pass: fp32 -> bf16, no-loop / branch-free / wide ----------
#define CVT_XBLK 6000            // 6000 * 256 * 8 = 12,288,000 = XELEMS
#define CVT_WBLK 128             //  128 * 256 * 8 =    262,144 = WELEMS
#define CVT_BPB  750             // x blocks per batch (6000 / 8)

__global__ __launch_bounds__(256)
void cvt_f32_bf16(const float* __restrict__ x, const float* __restrict__ W,
                  __bf16* __restrict__ xb, __bf16* __restrict__ Wb) {
    const int blk = blockIdx.x;
    const float* __restrict__ src;
    __bf16* __restrict__ dst;
    size_t base;
    if (blk < CVT_XBLK) {
        const int b = blk & 7;               // batch -> XCD (matches GEMM)
        const int c = blk >> 3;              // chunk within batch [0, 750)
        base = ((size_t)b * CVT_BPB + c) * (256 * 8) + (size_t)threadIdx.x * 8;
        src = x;  dst = xb;
    } else {
        base = (size_t)(blk - CVT_XBLK) * (256 * 8) + (size_t)threadIdx.x * 8;
        src = W;  dst = Wb;
    }
    const f32x8 v = *reinterpret_cast<const f32x8*>(src + base);
    bf16x8 h;
#pragma unroll
    for (int e = 0; e < 8; ++e) h[e] = (__bf16)v[e];
    *reinterpret_cast<bf16x8*>(dst + base) = h;
}

// ---------------- main GEMM: A JIT global->reg, W via verified LDS pipeline ------
// Round-7 structure (K-split wave pairs, 2 barriers + counted vmcnt, LDS fold)
// with ONE change: A is no longer staged in LDS. Each lane loads its 4 MFMA
// A-fragments (contiguous 16B of a gathered x-row, LINEAR address - no swizzle
// needed) straight from global inside the compute phase. x is 3 MB/batch ->
// L2-resident on the pinned XCD (L2 was ~55% busy; the LDS port was ~100%).
// Live ranges are intra-phase only (load->use between two barriers), so this is
// the proven fallback-kernel pattern, NOT the failed cross-barrier reg-prefetch.
//   LDS traffic per block-tile: 96 KB -> 48 KB (W DMA-write 16 + B ds_read 32).
//   The 385 MB of A gather-redundancy now rides the half-idle L2, not the port.
// W pipeline per tile per wave: 2 DMAs -> manual s_waitcnt vmcnt(2); the
// compiler tracks the DMA builtins, so its own waits for the A-loads are
// counted (vmcnt(2)) and never drain the W prefetch.
__global__ __launch_bounds__(512, 4)
void spiral_gemm_bf16(const __bf16* __restrict__ xb,    // (B, N, F) bf16 (ws)
                      const __bf16* __restrict__ Wb,    // (OUT, K) bf16 (ws)
                      const float*  __restrict__ bias,  // (OUT,) fp32
                      const int*    __restrict__ idx,   // (N, S) int32
                      const float*  __restrict__ zp,    // (N,) fp32
                      float*        __restrict__ out)   // (B, N, OUT) fp32
{
    __shared__ char smem[73728];                         // 72 KB -> 2 blocks/CU
    auto Ws = reinterpret_cast<__bf16(*)[ODIM * BK]>(smem);          // 2 x 16 KB
    int*   idxS    = reinterpret_cast<int*>(smem + 32768);           // 8 KB
    float* scratch = reinterpret_cast<float*>(smem);     // fold reuse (68 KB)

    const int tid   = threadIdx.x;
    const int wave  = tid >> 6;                // 0..7
    const int lane  = tid & 63;
    const int batch = blockIdx.x & 7;          // round-robin -> same XCD per batch
    const int n0    = (blockIdx.x >> 3) * BM;

    const int lrow8 = lane >> 3;               // row within the 8-row DMA group
    const int clog  = (lane & 7) ^ lrow8;      // inverse-swizzled 16B chunk (W DMA)

    const __bf16* xbase = xb + (size_t)batch * (NPTS * FDIM);

    // --- preload all gather indices for this block's 128 rows into LDS ---
    {
        const int row  = tid >> 2, q4 = tid & 3;      // 512 thr x int4 = 2048 ints
        const int n    = n0 + row;
        const int nrow = n < NPTS ? n : NPTS - 1;
        const int4* s4 = reinterpret_cast<const int4*>(idx + nrow * SDIM + q4 * 4);
        int4* d4       = reinterpret_cast<int4*>(&idxS[row * SDIM + q4 * 4]);
        d4[0] = s4[0];
    }
    __syncthreads();   // full drain OK here, once

    const int q    = wave >> 1;                // output sub-tile 0..3 (2x2)
    const int kkw  = wave & 1;                 // this wave's K-half
    const int wm   = (q >> 1) * 64;            // 0,64
    const int wn   = (q & 1) * 64;             // 0,64
    const int lrow = lane & 15;
    const int quad = lane >> 4;
    const int ph   = (kkw * 4 + quad) ^ (lrow & 7);   // swizzled chunk (verified)

    // per-lane gather rows for this lane's 4 A-fragments (MFMA A rows)
    int arow[4];
#pragma unroll
    for (int i = 0; i < 4; ++i) arow[i] = wm + i * 16 + lrow;

    int gCurA[4], gNextA[4];
#pragma unroll
    for (int i = 0; i < 4; ++i) gCurA[i] = idxS[arow[i] * SDIM + 0];

    // --- W DMA: 2 instrs per wave (8 rows each), verified swizzle ---
    auto issueW = [&](int buf, int kt) {
#pragma unroll
        for (int p = 0; p < 2; ++p) {
            const int r0 = (p * 8 + wave) * 8;
            const __bf16* gw = Wb + (size_t)(r0 + lrow8) * KDIM + kt * BK + clog * 8;
            __builtin_amdgcn_global_load_lds(AS1(gw), AS3(&Ws[buf][r0 * BK]), 16, 0, 0);
        }
    };

    f32x4 acc[4][4];
#pragma unroll
    for (int i = 0; i < 4; ++i)
#pragma unroll
        for (int j = 0; j < 4; ++j)
            acc[i][j] = f32x4{0.f, 0.f, 0.f, 0.f};

    // A column offset within x-row: f0 (0/64) + this wave's K-half + quad chunk
    const int acol = kkw * 32 + quad * 8;

    auto compute = [&](int buf, int f0, const int* gA) {
        bf16x8 a[4], b[4];
#pragma unroll
        for (int i = 0; i < 4; ++i)            // JIT global loads, linear address
            a[i] = *reinterpret_cast<const bf16x8*>(
                xbase + (size_t)gA[i] * FDIM + f0 + acol);
#pragma unroll
        for (int j = 0; j < 4; ++j)
            b[j] = *reinterpret_cast<const bf16x8*>(
                &Ws[buf][(wn + j * 16 + lrow) * BK + ph * 8]);
#pragma unroll
        for (int i = 0; i < 4; ++i)
#pragma unroll
            for (int j = 0; j < 4; ++j)
                acc[i][j] = __builtin_amdgcn_mfma_f32_16x16x32_bf16(
                    a[i], b[j], acc[i][j], 0, 0, 0);
    };

    // preamble: W tile 0 -> buf0
    issueW(0, 0);

    for (int t = 0; t < 16; ++t) {
        // ---- even kt = 2t (s=t, f0=0): compute buf0, prefetch W(2t+1) -> buf1
        issueW(1, 2 * t + 1);
        asm volatile("s_waitcnt vmcnt(2)" ::: "memory");  // W(2t) done, W(2t+1) in flight
        asm volatile("s_barrier" ::: "memory");
        if (t < 15) {
#pragma unroll
            for (int i = 0; i < 4; ++i)
                gNextA[i] = idxS[arow[i] * SDIM + t + 1]; // lgkm, hidden by compute
        }
        compute(0, 0, gCurA);
        asm volatile("s_barrier" ::: "memory");

        // ---- odd kt = 2t+1 (s=t, f0=64): compute buf1, prefetch W(2t+2) -> buf0
        if (t < 15) {
            issueW(0, 2 * t + 2);
            asm volatile("s_waitcnt vmcnt(2)" ::: "memory");
        } else {
            asm volatile("s_waitcnt vmcnt(0)" ::: "memory");
        }
        asm volatile("s_barrier" ::: "memory");
        compute(1, 64, gCurA);
        asm volatile("s_barrier" ::: "memory");
#pragma unroll
        for (int i = 0; i < 4; ++i) gCurA[i] = gNextA[i];
    }

    // --- fold the K-halves: kk=1 waves store partials, kk=0 waves add ---
    __syncthreads();                           // all compute LDS reads complete
    float* sc = scratch + q * (64 * SCW);      // col-major [col 64][row SCW]
    if (kkw == 1) {
#pragma unroll
        for (int i = 0; i < 4; ++i)
#pragma unroll
            for (int j = 0; j < 4; ++j)
                *reinterpret_cast<f32x4*>(
                    &sc[(j * 16 + lrow) * SCW + i * 16 + quad * 4]) = acc[i][j];
    }
    __syncthreads();
    if (kkw == 0) {
#pragma unroll
        for (int i = 0; i < 4; ++i)
#pragma unroll
            for (int j = 0; j < 4; ++j)
                acc[i][j] += *reinterpret_cast<const f32x4*>(
                    &sc[(j * 16 + lrow) * SCW + i * 16 + quad * 4]);

        // epilogue: bias + relu + zero_padding; C/D: col=lane&15, row=quad*4+reg
#pragma unroll
        for (int i = 0; i < 4; ++i) {
#pragma unroll
            for (int r = 0; r < 4; ++r) {
                const int row = wm + i * 16 + quad * 4 + r;
                const int n   = n0 + row;
                if (n < NPTS) {
                    const float z = zp[n];
                    float* orow   = out + ((size_t)batch * NPTS + n) * ODIM;
#pragma unroll
                    for (int j = 0; j < 4; ++j) {
                        const int col = wn + j * 16 + lrow;
                        float v = acc[i][j][r] + bias[col];
                        v = fmaxf(v, 0.f);
                        orow[col] = v * z;
                    }
                }
            }
        }
    }
}

// ---------------- fallback: fp32 direct, no ws (round-2 kernel) ----------------
#define LDA 72
#define BMF 128
__global__ __launch_bounds__(256, 2)
void spiral_gemm_fp32(const float* __restrict__ x, const float* __restrict__ W,
                      const float* __restrict__ bias, const int* __restrict__ idx,
                      const float* __restrict__ zp, float* __restrict__ out)
{
    __shared__ __bf16 Asf[BMF * LDA];
    __shared__ __bf16 Wsf[ODIM * LDA];
    const int tid = threadIdx.x, wave = tid >> 6, lane = tid & 63;
    const int m0 = blockIdx.x * BMF;
    const int srow = tid >> 3, schunk = tid & 7;
    int a_n[4]; const float* a_xb[4];
#pragma unroll
    for (int p = 0; p < 4; ++p) {
        int m = m0 + srow + p * 32, bb = m / NPTS;
        a_n[p] = m - bb * NPTS; a_xb[p] = x + (size_t)bb * (NPTS * FDIM);
    }
    f32x4 acc[4][4];
#pragma unroll
    for (int i = 0; i < 4; ++i)
#pragma unroll
        for (int j = 0; j < 4; ++j) acc[i][j] = f32x4{0.f,0.f,0.f,0.f};
    const int wm = (wave >> 1) * 64, wn = (wave & 1) * 64;
    const int lrow = lane & 15, quad = lane >> 4;
    for (int kt = 0; kt < KDIM / 64; ++kt) {
        const int s = kt >> 1, f0 = (kt & 1) * 64;
        __syncthreads();
#pragma unroll
        for (int p = 0; p < 4; ++p) {
            const int r = srow + p * 32;
            const int g = idx[a_n[p] * SDIM + s];
            const f32x8 v = *reinterpret_cast<const f32x8*>(
                a_xb[p] + (size_t)g * FDIM + f0 + schunk * 8);
            bf16x8 h;
#pragma unroll
            for (int e = 0; e < 8; ++e) h[e] = (__bf16)v[e];
            *reinterpret_cast<bf16x8*>(&Asf[r * LDA + schunk * 8]) = h;
            const f32x8 w = *reinterpret_cast<const f32x8*>(
                W + (size_t)r * KDIM + kt * 64 + schunk * 8);
            bf16x8 hw;
#pragma unroll
            for (int e = 0; e < 8; ++e) hw[e] = (__bf16)w[e];
            *reinterpret_cast<bf16x8*>(&Wsf[r * LDA + schunk * 8]) = hw;
        }
        __syncthreads();
#pragma unroll
        for (int kk = 0; kk < 2; ++kk) {
            const int koff = kk * 32 + quad * 8;
            bf16x8 a[4], b[4];
#pragma unroll
            for (int i = 0; i < 4; ++i)
                a[i] = *reinterpret_cast<const bf16x8*>(&Asf[(wm + i*16 + lrow)*LDA + koff]);
#pragma unroll
            for (int j = 0; j < 4; ++j)
                b[j] = *reinterpret_cast<const bf16x8*>(&Wsf[(wn + j*16 + lrow)*LDA + koff]);
#pragma unroll
            for (int i = 0; i < 4; ++i)
#pragma unroll
                for (int j = 0; j < 4; ++j)
                    acc[i][j] = __builtin_amdgcn_mfma_f32_16x16x32_bf16(a[i], b[j], acc[i][j], 0,0,0);
        }
    }
#pragma unroll
    for (int i = 0; i < 4; ++i)
#pragma unroll
        for (int r = 0; r < 4; ++r) {
            const int row = wm + i * 16 + quad * 4 + r;
            const int m = m0 + row, bb = m / NPTS, nnn = m - bb * NPTS;
            const float z = zp[nnn];
            float* orow = out + (size_t)m * ODIM;
#pragma unroll
            for (int j = 0; j < 4; ++j) {
                const int col = wn + j * 16 + lrow;
                float v = acc[i][j][r] + bias[col];
                orow[col] = fmaxf(v, 0.f) * z;
            }
        }
}

extern "C" void kernel_launch(void* const* d_in, const int* in_sizes, int n_in,
                              void* d_out, int out_size, void* d_ws, size_t ws_size,
                              hipStream_t stream) {
    const float* x    = (const float*)d_in[0];
    const float* W    = (const float*)d_in[1];
    const float* bias = (const float*)d_in[2];
    const int*   idx  = (const int*)d_in[3];
    const float* zp   = (const float*)d_in[4];
    float*       out  = (float*)d_out;

    if (ws_size >= XBYTES + WBYTES) {
        __bf16* xb = (__bf16*)d_ws;
        __bf16* Wb = (__bf16*)((char*)d_ws + XBYTES);
        cvt_f32_bf16<<<dim3(CVT_XBLK + CVT_WBLK), dim3(256), 0, stream>>>(x, W, xb, Wb);
        spiral_gemm_bf16<<<dim3(BATCH * NTILES), dim3(512), 0, stream>>>(
            xb, Wb, bias, idx, zp, out);
    } else {
        spiral_gemm_fp32<<<dim3(MTOT / BMF), dim3(256), 0, stream>>>(
            x, W, bias, idx, zp, out);
    }
}

// Round 9
// 155.114 us; speedup vs baseline: 1.5543x; 1.5543x over previous
//
#include <hip/hip_runtime.h>

#define BATCH 8
#define NPTS  12000
#define FDIM  128
#define SDIM  16
#define ODIM  128
#define KDIM  (SDIM * FDIM)      // 2048
#define MTOT  (BATCH * NPTS)     // 96000

#define BM 128
#define BK 64                    // row = 128 B = 8 x 16B chunks (verified swizzle)

#define NTILES 94                // ceil(12000 / 128)
#define XELEMS (BATCH * NPTS * FDIM)   // 12,288,000
#define WELEMS (ODIM * KDIM)           // 262,144
#define XBYTES ((size_t)XELEMS * 2)
#define WBYTES ((size_t)WELEMS * 2)

#define SCW 68                   // scratch stride (floats): 16B-aligned, bank-spread

typedef __bf16 bf16x4 __attribute__((ext_vector_type(4)));
typedef __bf16 bf16x8 __attribute__((ext_vector_type(8)));
typedef float  f32x4  __attribute__((ext_vector_type(4)));
typedef float  f32x8  __attribute__((ext_vector_type(8)));

#define AS1(p) ((const __attribute__((address_space(1))) void*)(p))
#define AS3(p) ((__attribute__((address_space(3))) void*)(p))

// ---------------- pre-pass: fp32 -> bf16, no-loop / branch-free / wide ----------
#define CVT_XBLK 6000            // 6000 * 256 * 8 = 12,288,000 = XELEMS
#define CVT_WBLK 128             //  128 * 256 * 8 =    262,144 = WELEMS
#define CVT_BPB  750             // x blocks per batch (6000 / 8)

__global__ __launch_bounds__(256)
void cvt_f32_bf16(const float* __restrict__ x, const float* __restrict__ W,
                  __bf16* __restrict__ xb, __bf16* __restrict__ Wb) {
    const int blk = blockIdx.x;
    const float* __restrict__ src;
    __bf16* __restrict__ dst;
    size_t base;
    if (blk < CVT_XBLK) {
        const int b = blk & 7;               // batch -> XCD (matches GEMM)
        const int c = blk >> 3;              // chunk within batch [0, 750)
        base = ((size_t)b * CVT_BPB + c) * (256 * 8) + (size_t)threadIdx.x * 8;
        src = x;  dst = xb;
    } else {
        base = (size_t)(blk - CVT_XBLK) * (256 * 8) + (size_t)threadIdx.x * 8;
        src = W;  dst = Wb;
    }
    const f32x8 v = *reinterpret_cast<const f32x8*>(src + base);
    bf16x8 h;
#pragma unroll
    for (int e = 0; e < 8; ++e) h[e] = (__bf16)v[e];
    *reinterpret_cast<bf16x8*>(dst + base) = h;
}

// ---------------- main GEMM: round-7 verified structure + T5 setprio -------------
// Round-7 (61.7us, best): 8 waves, K-split wave pairs (waves 2q/2q+1 share the
// 64x64 output sub-tile q, each computes one K-half), dbuf LDS via
// global_load_lds, 2 barriers + counted vmcnt(4) per K-tile, end-of-kernel LDS
// fold. ONE additive change: s_setprio(1) around the MFMA cluster (T5). The
// 16 waves/CU contend on a ~72%-busy LDS port, so inside each phase waves skew
// (some still in ds_read, some MFMA-ready); setprio biases the CU scheduler
// toward the MFMA-ready waves (m224 mechanism).
__global__ __launch_bounds__(512, 4)
void spiral_gemm_bf16(const __bf16* __restrict__ xb,    // (B, N, F) bf16 (ws)
                      const __bf16* __restrict__ Wb,    // (OUT, K) bf16 (ws)
                      const float*  __restrict__ bias,  // (OUT,) fp32
                      const int*    __restrict__ idx,   // (N, S) int32
                      const float*  __restrict__ zp,    // (N,) fp32
                      float*        __restrict__ out)   // (B, N, OUT) fp32
{
    __shared__ char smem[73728];                         // 72 KB -> 2 blocks/CU
    auto As = reinterpret_cast<__bf16(*)[BM * BK]>(smem);            // 2 x 16 KB
    auto Ws = reinterpret_cast<__bf16(*)[ODIM * BK]>(smem + 32768);  // 2 x 16 KB
    int*   idxS    = reinterpret_cast<int*>(smem + 65536);           // 8 KB
    float* scratch = reinterpret_cast<float*>(smem);     // fold reuse (68 KB)

    const int tid   = threadIdx.x;
    const int wave  = tid >> 6;                // 0..7
    const int lane  = tid & 63;
    const int batch = blockIdx.x & 7;          // round-robin -> same XCD per batch
    const int n0    = (blockIdx.x >> 3) * BM;

    const int lrow8 = lane >> 3;               // row within the 8-row DMA group
    const int clog  = (lane & 7) ^ lrow8;      // inverse-swizzled 16B chunk (DMA src)

    const __bf16* xbase = xb + (size_t)batch * (NPTS * FDIM);

    // --- preload all gather indices for this block's 128 rows into LDS ---
    {
        const int row  = tid >> 2, q4 = tid & 3;      // 512 thr x int4 = 2048 ints
        const int n    = n0 + row;
        const int nrow = n < NPTS ? n : NPTS - 1;
        const int4* s4 = reinterpret_cast<const int4*>(idx + nrow * SDIM + q4 * 4);
        int4* d4       = reinterpret_cast<int4*>(&idxS[row * SDIM + q4 * 4]);
        d4[0] = s4[0];
    }
    __syncthreads();   // full drain OK here, once

    int rrow[2];
#pragma unroll
    for (int p = 0; p < 2; ++p) rrow[p] = (p * 8 + wave) * 8 + lrow8;

    int gCur[2], gNext[2];
#pragma unroll
    for (int p = 0; p < 2; ++p) gCur[p] = idxS[rrow[p] * SDIM + 0];

    // --- DMA issue: per wave 2 A-groups + 2 W-groups (verified round-4 pattern) ---
    auto issue = [&](int buf, int kt, const int* g) {
        const int f0 = (kt & 1) * BK;
#pragma unroll
        for (int p = 0; p < 2; ++p) {
            const int r0 = (p * 8 + wave) * 8;
            const __bf16* ga = xbase + (size_t)g[p] * FDIM + f0 + clog * 8;
            __builtin_amdgcn_global_load_lds(AS1(ga), AS3(&As[buf][r0 * BK]), 16, 0, 0);
            const __bf16* gw = Wb + (size_t)(r0 + lrow8) * KDIM + kt * BK + clog * 8;
            __builtin_amdgcn_global_load_lds(AS1(gw), AS3(&Ws[buf][r0 * BK]), 16, 0, 0);
        }
    };

    f32x4 acc[4][4];
#pragma unroll
    for (int i = 0; i < 4; ++i)
#pragma unroll
        for (int j = 0; j < 4; ++j)
            acc[i][j] = f32x4{0.f, 0.f, 0.f, 0.f};

    const int q    = wave >> 1;                // output sub-tile 0..3 (2x2)
    const int kkw  = wave & 1;                 // this wave's K-half
    const int wm   = (q >> 1) * 64;            // 0,64
    const int wn   = (q & 1) * 64;             // 0,64
    const int lrow = lane & 15;
    const int quad = lane >> 4;
    const int ph   = (kkw * 4 + quad) ^ (lrow & 7);   // swizzled chunk (verified)

    auto compute = [&](int buf) {
        bf16x8 a[4], b[4];
#pragma unroll
        for (int i = 0; i < 4; ++i)
            a[i] = *reinterpret_cast<const bf16x8*>(
                &As[buf][(wm + i * 16 + lrow) * BK + ph * 8]);
#pragma unroll
        for (int j = 0; j < 4; ++j)
            b[j] = *reinterpret_cast<const bf16x8*>(
                &Ws[buf][(wn + j * 16 + lrow) * BK + ph * 8]);
        __builtin_amdgcn_s_setprio(1);         // T5: favor MFMA-ready waves
#pragma unroll
        for (int i = 0; i < 4; ++i)
#pragma unroll
            for (int j = 0; j < 4; ++j)
                acc[i][j] = __builtin_amdgcn_mfma_f32_16x16x32_bf16(
                    a[i], b[j], acc[i][j], 0, 0, 0);
        __builtin_amdgcn_s_setprio(0);
    };

    // preamble: tile 0 (s=0, f0=0) -> buf0
    issue(0, 0, gCur);

    for (int t = 0; t < 16; ++t) {
        // ---- even kt = 2t: compute buf0, issue tile 2t+1 (s=t, f0=64) -> buf1
        issue(1, 2 * t + 1, gCur);
        asm volatile("s_waitcnt vmcnt(4)" ::: "memory");
        asm volatile("s_barrier" ::: "memory");
        if (t < 15) {
#pragma unroll
            for (int p = 0; p < 2; ++p)
                gNext[p] = idxS[rrow[p] * SDIM + t + 1];  // lgkm, hidden by compute
        }
        compute(0);
        asm volatile("s_barrier" ::: "memory");

        // ---- odd kt = 2t+1: compute buf1, issue tile 2t+2 (s=t+1, f0=0) -> buf0
        if (t < 15) {
            issue(0, 2 * t + 2, gNext);
            asm volatile("s_waitcnt vmcnt(4)" ::: "memory");
        } else {
            asm volatile("s_waitcnt vmcnt(0)" ::: "memory");
        }
        asm volatile("s_barrier" ::: "memory");
        compute(1);
        asm volatile("s_barrier" ::: "memory");
#pragma unroll
        for (int p = 0; p < 2; ++p) gCur[p] = gNext[p];
    }

    // --- fold the K-halves: kk=1 waves store partials, kk=0 waves add ---
    __syncthreads();                           // all compute LDS reads complete
    float* sc = scratch + q * (64 * SCW);      // col-major [col 64][row SCW]
    if (kkw == 1) {
#pragma unroll
        for (int i = 0; i < 4; ++i)
#pragma unroll
            for (int j = 0; j < 4; ++j)
                *reinterpret_cast<f32x4*>(
                    &sc[(j * 16 + lrow) * SCW + i * 16 + quad * 4]) = acc[i][j];
    }
    __syncthreads();
    if (kkw == 0) {
#pragma unroll
        for (int i = 0; i < 4; ++i)
#pragma unroll
            for (int j = 0; j < 4; ++j)
                acc[i][j] += *reinterpret_cast<const f32x4*>(
                    &sc[(j * 16 + lrow) * SCW + i * 16 + quad * 4]);

        // epilogue: bias + relu + zero_padding; C/D: col=lane&15, row=quad*4+reg
#pragma unroll
        for (int i = 0; i < 4; ++i) {
#pragma unroll
            for (int r = 0; r < 4; ++r) {
                const int row = wm + i * 16 + quad * 4 + r;
                const int n   = n0 + row;
                if (n < NPTS) {
                    const float z = zp[n];
                    float* orow   = out + ((size_t)batch * NPTS + n) * ODIM;
#pragma unroll
                    for (int j = 0; j < 4; ++j) {
                        const int col = wn + j * 16 + lrow;
                        float v = acc[i][j][r] + bias[col];
                        v = fmaxf(v, 0.f);
                        orow[col] = v * z;
                    }
                }
            }
        }
    }
}

// ---------------- fallback: fp32 direct, no ws (round-2 kernel) ----------------
#define LDA 72
#define BMF 128
__global__ __launch_bounds__(256, 2)
void spiral_gemm_fp32(const float* __restrict__ x, const float* __restrict__ W,
                      const float* __restrict__ bias, const int* __restrict__ idx,
                      const float* __restrict__ zp, float* __restrict__ out)
{
    __shared__ __bf16 Asf[BMF * LDA];
    __shared__ __bf16 Wsf[ODIM * LDA];
    const int tid = threadIdx.x, wave = tid >> 6, lane = tid & 63;
    const int m0 = blockIdx.x * BMF;
    const int srow = tid >> 3, schunk = tid & 7;
    int a_n[4]; const float* a_xb[4];
#pragma unroll
    for (int p = 0; p < 4; ++p) {
        int m = m0 + srow + p * 32, bb = m / NPTS;
        a_n[p] = m - bb * NPTS; a_xb[p] = x + (size_t)bb * (NPTS * FDIM);
    }
    f32x4 acc[4][4];
#pragma unroll
    for (int i = 0; i < 4; ++i)
#pragma unroll
        for (int j = 0; j < 4; ++j) acc[i][j] = f32x4{0.f,0.f,0.f,0.f};
    const int wm = (wave >> 1) * 64, wn = (wave & 1) * 64;
    const int lrow = lane & 15, quad = lane >> 4;
    for (int kt = 0; kt < KDIM / 64; ++kt) {
        const int s = kt >> 1, f0 = (kt & 1) * 64;
        __syncthreads();
#pragma unroll
        for (int p = 0; p < 4; ++p) {
            const int r = srow + p * 32;
            const int g = idx[a_n[p] * SDIM + s];
            const f32x8 v = *reinterpret_cast<const f32x8*>(
                a_xb[p] + (size_t)g * FDIM + f0 + schunk * 8);
            bf16x8 h;
#pragma unroll
            for (int e = 0; e < 8; ++e) h[e] = (__bf16)v[e];
            *reinterpret_cast<bf16x8*>(&Asf[r * LDA + schunk * 8]) = h;
            const f32x8 w = *reinterpret_cast<const f32x8*>(
                W + (size_t)r * KDIM + kt * 64 + schunk * 8);
            bf16x8 hw;
#pragma unroll
            for (int e = 0; e < 8; ++e) hw[e] = (__bf16)w[e];
            *reinterpret_cast<bf16x8*>(&Wsf[r * LDA + schunk * 8]) = hw;
        }
        __syncthreads();
#pragma unroll
        for (int kk = 0; kk < 2; ++kk) {
            const int koff = kk * 32 + quad * 8;
            bf16x8 a[4], b[4];
#pragma unroll
            for (int i = 0; i < 4; ++i)
                a[i] = *reinterpret_cast<const bf16x8*>(&Asf[(wm + i*16 + lrow)*LDA + koff]);
#pragma unroll
            for (int j = 0; j < 4; ++j)
                b[j] = *reinterpret_cast<const bf16x8*>(&Wsf[(wn + j*16 + lrow)*LDA + koff]);
#pragma unroll
            for (int i = 0; i < 4; ++i)
#pragma unroll
                for (int j = 0; j < 4; ++j)
                    acc[i][j] = __builtin_amdgcn_mfma_f32_16x16x32_bf16(a[i], b[j], acc[i][j], 0,0,0);
        }
    }
#pragma unroll
    for (int i = 0; i < 4; ++i)
#pragma unroll
        for (int r = 0; r < 4; ++r) {
            const int row = wm + i * 16 + quad * 4 + r;
            const int m = m0 + row, bb = m / NPTS, nnn = m - bb * NPTS;
            const float z = zp[nnn];
            float* orow = out + (size_t)m * ODIM;
#pragma unroll
            for (int j = 0; j < 4; ++j) {
                const int col = wn + j * 16 + lrow;
                float v = acc[i][j][r] + bias[col];
                orow[col] = fmaxf(v, 0.f) * z;
            }
        }
}

extern "C" void kernel_launch(void* const* d_in, const int* in_sizes, int n_in,
                              void* d_out, int out_size, void* d_ws, size_t ws_size,
                              hipStream_t stream) {
    const float* x    = (const float*)d_in[0];
    const float* W    = (const float*)d_in[1];
    const float* bias = (const float*)d_in[2];
    const int*   idx  = (const int*)d_in[3];
    const float* zp   = (const float*)d_in[4];
    float*       out  = (float*)d_out;

    if (ws_size >= XBYTES + WBYTES) {
        __bf16* xb = (__bf16*)d_ws;
        __bf16* Wb = (__bf16*)((char*)d_ws + XBYTES);
        cvt_f32_bf16<<<dim3(CVT_XBLK + CVT_WBLK), dim3(256), 0, stream>>>(x, W, xb, Wb);
        spiral_gemm_bf16<<<dim3(BATCH * NTILES), dim3(512), 0, stream>>>(
            xb, Wb, bias, idx, zp, out);
    } else {
        spiral_gemm_fp32<<<dim3(MTOT / BMF), dim3(256), 0, stream>>>(
            x, W, bias, idx, zp, out);
    }
}